// Round 3
// baseline (432.300 us; speedup 1.0000x reference)
//
#include <hip/hip_runtime.h>
#include <hip/hip_bf16.h>
#include <hip/hip_fp16.h>

// ---------------------------------------------------------------------------
// EnhancedRGCN (3-layer GAT), N=100000 nodes, E=3200000 edges, D=32.
// CSR-by-dst via FIXED-CAPACITY bucket binning (bucket = dst>>7, 128 nodes,
// CAPB=6144 slots). R13: k_bin LDS-staged bucket-grouped run writeback.
// R15: k_edge HEAD-SPLIT for L2 residency. h16 is stored as two 3.2MB
// channel-half arrays (h16a = ch 0-15 / head 0, h16b = ch 16-31 / head 1);
// each k_edge block processes ONE head (H=2) or one channel half (H=1) for
// 8 nodes, head = blockIdx&1. With round-robin block->XCD dispatch, even
// blocks (head 0) land on even XCDs and gather ONLY h16a (3.2MB + 0.4MB a_s
// < 4MB per-XCD L2) -> gathers become L2-resident instead of ~50% miss at
// 6.4MB working set. a_s/a_d stored head-major. src_sorted pass-A reads and
// out stores are non-temporal to keep streams from evicting the gather set.
// Pass B: 4 slots x 8 channel-lanes per node, 16 edges/node/iter (R13 depth:
// 2 ds_read_b128 + 4 half2 gathers + 8 fma per lane). R14's 32-wide was a
// regression (pad waste + VGPR) — reverted. No segment-max; no float atomics.
// ---------------------------------------------------------------------------

#define NPB  128    // nodes per bucket (dst>>7)
#define CAPB 6144   // slots per bucket (exact mean ~4092, >30 sigma room)
#define PAD_SENTINEL 0xFFFFFFFFu

// ---------------- pass 1: bin edges into fixed bucket regions --------------
__global__ void __launch_bounds__(1024)
k_bin(const int* __restrict__ src, const int* __restrict__ dst,
      int* __restrict__ bucket_cursor, unsigned int* __restrict__ pairs,
      int e, int nb) {
    __shared__ int h[1024];                 // per-bucket count (this block)
    __shared__ int bs[1024];                // block-local exclusive base
    __shared__ int cb[1024];                // global (relative) reservation
    __shared__ unsigned int stage[8192];    // bucket-grouped staged pairs
    int t = threadIdx.x;
    h[t] = 0;
    __syncthreads();
    int e4 = e >> 2;
    int base4 = blockIdx.x * 2048;          // 1024 threads x 2 int4 each
    int boff[8];                            // (bucket<<16) | rank, or -1
    unsigned int pk[8];
#pragma unroll
    for (int k = 0; k < 2; k++) {
        int i4 = base4 + k * 1024 + t;
        if (i4 < e4) {
            int4 dv = ((const int4*)dst)[i4];
            int4 sv = ((const int4*)src)[i4];
            const int* dd = (const int*)&dv;
            const int* ss = (const int*)&sv;
#pragma unroll
            for (int j = 0; j < 4; j++) {
                int q = 4 * k + j;
                int d = dd[j];
                int b = d >> 7;
                pk[q] = ((unsigned int)ss[j] << 7) | (unsigned int)(d & 127);
                int off = atomicAdd(&h[b], 1);
                boff[q] = (b << 16) | off;
            }
        } else {
#pragma unroll
            for (int j = 0; j < 4; j++) boff[4 * k + j] = -1;
        }
    }
    __syncthreads();
    if (t >= 128 && t - 128 < nb) {
        int b = t - 128;
        int c = h[b];
        cb[b] = c ? atomicAdd(&bucket_cursor[b], c) : 0;
    }
    if (t < 64) {                           // wave 0: scan 1024 bins (16/lane)
        int sum = 0;
#pragma unroll
        for (int j = 0; j < 16; j++) sum += h[t * 16 + j];
        int run = sum;
#pragma unroll
        for (int off = 1; off < 64; off <<= 1) {
            int v = __shfl_up(run, off, 64);
            if (t >= off) run += v;
        }
        int base = run - sum;               // exclusive
#pragma unroll
        for (int j = 0; j < 16; j++) {
            int b = t * 16 + j;
            bs[b] = base;
            base += h[b];
        }
    }
    __syncthreads();
#pragma unroll
    for (int q = 0; q < 8; q++) {           // scatter into bucket-grouped LDS
        if (boff[q] >= 0) {
            int b = boff[q] >> 16;
            stage[bs[b] + (boff[q] & 0xFFFF)] = pk[q];
        }
    }
    __syncthreads();
    int wv = t >> 6, ln = t & 63;
    for (int b = wv; b < nb; b += 16) {
        int c = h[b];
        if (c == 0) continue;
        int gb = cb[b];
        int room = CAPB - gb;               // overflow guard (relative cursor)
        if (c > room) c = (room > 0) ? room : 0;
        unsigned int* dp = pairs + (size_t)b * CAPB + gb;
        const unsigned int* sp = stage + bs[b];
        for (int o = ln; o < c; o += 64) dp[o] = sp[o];
    }
    if (blockIdx.x == 0 && t < (e & 3)) {   // tail (e not multiple of 4)
        int i = (e & ~3) + t;
        int d = dst[i];
        int b = d >> 7;
        int r = atomicAdd(&bucket_cursor[b], 1);
        if (r < CAPB)
            pairs[(size_t)b * CAPB + r] =
                ((unsigned int)src[i] << 7) | (unsigned int)(d & 127);
    }
}

// ---------------- pass 2: per-bucket LDS sort -> rowinfo + src_sorted ------
__global__ void __launch_bounds__(512)
k_bucket_sort(const unsigned int* __restrict__ pairs,
              const int* __restrict__ bucket_cursor,
              int2* __restrict__ rowinfo, int* __restrict__ src_sorted,
              int n) {
    __shared__ int cnt[NPB];
    __shared__ int cur[NPB];
    __shared__ int total;
    __shared__ unsigned int lp[CAPB];
    __shared__ int op[CAPB];
    int b = blockIdx.x;
    int t = threadIdx.x;
    int bbase = b * CAPB;
    int m = bucket_cursor[b];               // relative cursor = exact count
    if (m > CAPB) m = CAPB;
    if (t < NPB) cnt[t] = 0;
    __syncthreads();
    for (int cb = 0; cb < m; cb += 4096) {
        unsigned int pv[8];
#pragma unroll
        for (int u = 0; u < 8; u++) {
            int i = cb + u * 512 + t;
            pv[u] = (i < m) ? pairs[bbase + i] : PAD_SENTINEL;
        }
#pragma unroll
        for (int u = 0; u < 8; u++) {
            int i = cb + u * 512 + t;
            if (i < m) lp[i] = pv[u];
            if (pv[u] != PAD_SENTINEL) atomicAdd(&cnt[pv[u] & 127], 1);
        }
    }
    __syncthreads();
    if (t < 64) {                       // wave 0 only: shfl scan over 128 bins
        int c0 = cnt[2 * t];
        int c1 = cnt[2 * t + 1];
        int sum = c0 + c1;
        int run = sum;
#pragma unroll
        for (int off = 1; off < 64; off <<= 1) {
            int v = __shfl_up(run, off, 64);
            if (t >= off) run += v;
        }
        int ex = run - sum;             // exclusive
        cur[2 * t] = ex;
        cur[2 * t + 1] = ex + c0;
        int node = b * NPB + 2 * t;
        if (node < n) rowinfo[node] = make_int2(bbase + ex, c0);
        if (node + 1 < n) rowinfo[node + 1] = make_int2(bbase + ex + c0, c1);
        if (t == 63) total = run;       // dense entry count
    }
    __syncthreads();
    for (int cb = 0; cb < m; cb += 4096) {
        unsigned int pv[8];
        int of[8];
#pragma unroll
        for (int u = 0; u < 8; u++) {
            int i = cb + u * 512 + t;
            pv[u] = (i < m) ? lp[i] : PAD_SENTINEL;
        }
#pragma unroll
        for (int u = 0; u < 8; u++)
            if (pv[u] != PAD_SENTINEL) of[u] = atomicAdd(&cur[pv[u] & 127], 1);
#pragma unroll
        for (int u = 0; u < 8; u++)
            if (pv[u] != PAD_SENTINEL) op[of[u]] = (int)(pv[u] >> 7);
    }
    __syncthreads();
    int nt4 = (total + 3) >> 2;
    int4* dst4 = (int4*)(src_sorted + bbase);
    const int4* src4 = (const int4*)op;
    for (int i = t; i < nt4; i += 512) dst4[i] = src4[i];
}

// ---------------- per-layer dense transform ----------------
// Writes h split into channel-half arrays (h16a = ch 0-15, h16b = ch 16-31)
// and a_s/a_d HEAD-MAJOR ([H][n]).
template <int H>
__global__ void k_transform(const float* __restrict__ in, const float* __restrict__ W,
                            const float* __restrict__ att_s, const float* __restrict__ att_d,
                            __half* __restrict__ h16a, __half* __restrict__ h16b,
                            float* __restrict__ a_s, float* __restrict__ a_d, int n) {
    constexpr int C = 32 / H;
    __shared__ float Wl[32][33];
    __shared__ float xs[8][32];
    int t = threadIdx.x;
    for (int i = t; i < 1024; i += 256) Wl[i >> 5][i & 31] = W[i];
    int nl = t >> 5, o = t & 31;
    int node = blockIdx.x * 8 + nl;
    xs[nl][o] = (node < n) ? in[node * 32 + o] : 0.f;
    __syncthreads();
    float acc = 0.f;
#pragma unroll
    for (int k = 0; k < 32; k++) acc = fmaf(xs[nl][k], Wl[o][k], acc);
    if (node < n) {
        __half* hp = (o < 16) ? h16a : h16b;
        hp[node * 16 + (o & 15)] = __float2half_rn(acc);
        float vs = acc * att_s[o];
        float vd = acc * att_d[o];
#pragma unroll
        for (int m = C / 2; m >= 1; m >>= 1) {
            vs += __shfl_xor(vs, m, 64);
            vd += __shfl_xor(vd, m, 64);
        }
        if ((o % C) == 0) {
            int hh = o / C;
            a_s[hh * n + node] = vs;
            a_d[hh * n + node] = vd;
        }
    }
}

// ---------------- per-layer fused edge softmax + aggregation ----------------
// HEAD-SPLIT blocks: head = blockIdx&1, 8 nodes per block (half-wave/node).
// H=2: block gathers only its head's 3.2MB h-array + 0.4MB a_s -> L2-resident
//      per XCD (parity swizzle). H=1: head = channel half, alpha recomputed
//      per block from the shared a_s (400KB).
// Pass A: 32 lanes/node stride-32 over edges; stash (s,ex) int2; denom
//         partials. Pass B: 4 slots x 8 channel-lanes, 16 edges/node/iter
//         (2 ds_read_b128 + 4 half2 gathers + 8 fma per lane). Denominator:
//         5-level butterfly; acc: 2-level slot reduce.
// EPI: 0 = bias only (layer3), 1 = layer1 epilogue, 2 = elu+clip (layer2).
template <int H, int EPI>
__global__ void k_edge(const int2* __restrict__ rowinfo, const int* __restrict__ src_sorted,
                       const __half* __restrict__ h16a, const __half* __restrict__ h16b,
                       const float* __restrict__ a_s, const float* __restrict__ a_d,
                       const float* __restrict__ bias, const float* __restrict__ ea,
                       float* __restrict__ out, int n, float slope) {
    constexpr int CAP = 128;                  // entries per node
    constexpr int RSTR = 2 * CAP + 16;        // region stride in ints (+64B pad)
    __shared__ int lds_raw[8][RSTR];
    int head = blockIdx.x & 1;
    int grp = blockIdx.x >> 1;
    int nw = threadIdx.x >> 5;                // node slot 0..7
    int hl = threadIdx.x & 31;                // half-wave lane
    int node = grp * 8 + nw;
    if (node >= n) return;
    int2 bi = rowinfo[node];
    int beg = bi.x, deg = bi.y;
    int padB = (deg + 15) & ~15;

    const __half* hsrc = head ? h16b : h16a;
    const float* asp = a_s + (H == 2 ? head * n : 0);
    float adv = a_d[(H == 2 ? head * n : 0) + node];

    // ---- pass A: stash (s, ex) + denominator partials ----
    float dsum = 0.f;
    bool fast = (padB <= CAP);
    if (fast) {
        for (int idx = hl; idx < padB; idx += 32) {
            if (idx < deg) {
                int s = __builtin_nontemporal_load(src_sorted + beg + idx);
                float l = asp[s] + adv;
                l = fmaxf(l, l * slope);
                float e0 = __expf(l);
                dsum += e0;
                ((int2*)lds_raw[nw])[idx] = make_int2(s, __float_as_int(e0));
            } else {
                ((int2*)lds_raw[nw])[idx] = make_int2(0, 0);
            }
        }
    } else {
        for (int idx = hl; idx < deg; idx += 32) {
            int s = __builtin_nontemporal_load(src_sorted + beg + idx);
            float l = asp[s] + adv;
            l = fmaxf(l, l * slope);
            dsum += __expf(l);
        }
    }

    // ---- pass B: 4 slots x 8 channel-lanes per node; 16 edges/iter ----
    int e4 = hl >> 3;          // slot 0..3
    int l8 = hl & 7;           // channel pair 0..7 (within 16-ch half)
    int co = l8 << 2;          // byte offset into 32B half-row
    float acc0 = 0.f, acc1 = 0.f;
    const char* hbase = (const char*)hsrc;

    if (fast) {
        const int* lb = lds_raw[nw] + 4 * e4;
        for (int base = 0; base < padB; base += 16) {
            int4 q0 = *(const int4*)(lb + 2 * base);
            int4 q1 = *(const int4*)(lb + 2 * base + 16);
            __half2 h0 = *(const __half2*)(hbase + (unsigned)((q0.x << 5) + co));
            __half2 h1 = *(const __half2*)(hbase + (unsigned)((q0.z << 5) + co));
            __half2 h2 = *(const __half2*)(hbase + (unsigned)((q1.x << 5) + co));
            __half2 h3 = *(const __half2*)(hbase + (unsigned)((q1.z << 5) + co));
            float x0 = __int_as_float(q0.y), x1 = __int_as_float(q0.w);
            float x2 = __int_as_float(q1.y), x3 = __int_as_float(q1.w);
            acc0 = fmaf(x0, __half2float(__low2half(h0)), acc0);
            acc1 = fmaf(x0, __half2float(__high2half(h0)), acc1);
            acc0 = fmaf(x1, __half2float(__low2half(h1)), acc0);
            acc1 = fmaf(x1, __half2float(__high2half(h1)), acc1);
            acc0 = fmaf(x2, __half2float(__low2half(h2)), acc0);
            acc1 = fmaf(x2, __half2float(__high2half(h2)), acc1);
            acc0 = fmaf(x3, __half2float(__low2half(h3)), acc0);
            acc1 = fmaf(x3, __half2float(__high2half(h3)), acc1);
        }
    } else {
        for (int base = 0; base < deg; base += 16) {
#pragma unroll
            for (int j = 0; j < 4; j++) {
                int idx = base + e4 * 4 + j;
                int s = 0;
                float ex = 0.f;
                if (idx < deg) {
                    s = __builtin_nontemporal_load(src_sorted + beg + idx);
                    float l = asp[s] + adv;
                    l = fmaxf(l, l * slope);
                    ex = __expf(l);
                }
                __half2 hv = *(const __half2*)(hbase + (unsigned)((s << 5) + co));
                acc0 = fmaf(ex, __half2float(__low2half(hv)), acc0);
                acc1 = fmaf(ex, __half2float(__high2half(hv)), acc1);
            }
        }
    }

    // ---- denominator reduction (5-level half-wave butterfly) ----
#pragma unroll
    for (int m = 16; m >= 1; m >>= 1) dsum += __shfl_xor(dsum, m, 64);
    float invd = 1.f / (dsum + 1e-16f);

    // ---- reduce accs across the 4 slots (2 levels) ----
    acc0 += __shfl_xor(acc0, 8, 64);
    acc1 += __shfl_xor(acc1, 8, 64);
    acc0 += __shfl_xor(acc0, 16, 64);
    acc1 += __shfl_xor(acc1, 16, 64);

    if (hl < 8) {              // slot-0 lanes hold the result
        int ch = (head << 4) + l8 * 2;
        float2 bv = *(const float2*)(bias + ch);
        float v0 = fmaf(acc0, invd, bv.x);
        float v1 = fmaf(acc1, invd, bv.y);
        if (EPI == 1) {
            float s0 = tanhf(ea[0]);
            if (s0 < 0.1f) s0 = 1.0f;
            s0 *= 1.05f;
            v0 *= s0; v1 *= s0;
            v0 = (v0 > 0.f) ? v0 : expm1f(v0);
            v1 = (v1 > 0.f) ? v1 : expm1f(v1);
            v0 = fminf(3.f, fmaxf(-3.f, v0));
            v1 = fminf(3.f, fmaxf(-3.f, v1));
        } else if (EPI == 2) {
            v0 = (v0 > 0.f) ? v0 : expm1f(v0);
            v1 = (v1 > 0.f) ? v1 : expm1f(v1);
            v0 = fminf(3.f, fmaxf(-3.f, v0));
            v1 = fminf(3.f, fmaxf(-3.f, v1));
        }
        float2 r = make_float2(v0, v1);
        __builtin_nontemporal_store(*reinterpret_cast<const double*>(&r),
                                    reinterpret_cast<double*>(out + (size_t)node * 32 + ch));
    }
}

// ---------------------------------------------------------------------------
extern "C" void kernel_launch(void* const* d_in, const int* in_sizes, int n_in,
                              void* d_out, int out_size, void* d_ws, size_t ws_size,
                              hipStream_t stream) {
    const float* x   = (const float*)d_in[0];
    const int*   ei  = (const int*)d_in[1];
    const float* W1  = (const float*)d_in[2];
    const float* as1 = (const float*)d_in[3];
    const float* ad1 = (const float*)d_in[4];
    const float* b1  = (const float*)d_in[5];
    const float* ea1 = (const float*)d_in[6];
    const float* W2  = (const float*)d_in[7];
    const float* as2 = (const float*)d_in[8];
    const float* ad2 = (const float*)d_in[9];
    const float* b2  = (const float*)d_in[10];
    const float* W3  = (const float*)d_in[11];
    const float* as3 = (const float*)d_in[12];
    const float* ad3 = (const float*)d_in[13];
    const float* b3  = (const float*)d_in[14];
    float* out = (float*)d_out;

    const int n = in_sizes[0] / 32;   // 100000
    const int e = in_sizes[1] / 2;    // 3200000
    const int* src = ei;
    const int* dst = ei + e;
    const int nb = (n + NPB - 1) / NPB;   // 782 buckets

    char* w = (char*)d_ws;
    auto alloc = [&](size_t bytes) -> void* {
        void* p = (void*)w;
        w += (bytes + 255) & ~(size_t)255;
        return p;
    };
    __half* h16a    = (__half*)alloc((size_t)n * 16 * 2);
    __half* h16b    = (__half*)alloc((size_t)n * 16 * 2);
    float* a_s      = (float*)alloc((size_t)n * 2 * 4);
    float* a_d      = (float*)alloc((size_t)n * 2 * 4);
    float* bufA     = (float*)alloc((size_t)n * 32 * 4);
    float* bufB     = (float*)alloc((size_t)n * 32 * 4);
    int2* rowinfo   = (int2*)alloc((size_t)n * 8);
    int* bucket_cur = (int*)alloc((size_t)(nb + 1) * 4);
    int* src_sorted = (int*)alloc((size_t)nb * CAPB * 4);
    unsigned int* pairs = (unsigned int*)bufA;   // aliased (spills into bufB;
                                                 // both consumed pre-layer1)

    // ---- build CSR by dst (LDS-staged bucket binning, exact counts) ----
    hipMemsetAsync(bucket_cur, 0, (size_t)nb * 4, stream);   // relative cursors
    int e4 = e >> 2;
    k_bin<<<(e4 + 2047) / 2048, 1024, 0, stream>>>(src, dst, bucket_cur, pairs, e, nb);
    k_bucket_sort<<<nb, 512, 0, stream>>>(pairs, bucket_cur, rowinfo, src_sorted, n);

    const int tgrid = (n + 7) / 8;
    const int egrid = 2 * ((n + 7) / 8);   // head-split: 2 blocks per 8 nodes

    // ---- layer 1 ----
    k_transform<2><<<tgrid, 256, 0, stream>>>(x, W1, as1, ad1, h16a, h16b, a_s, a_d, n);
    k_edge<2, 1><<<egrid, 256, 0, stream>>>(rowinfo, src_sorted, h16a, h16b, a_s, a_d, b1, ea1, bufA, n, 0.01f);

    // ---- layer 2 ----
    k_transform<2><<<tgrid, 256, 0, stream>>>(bufA, W2, as2, ad2, h16a, h16b, a_s, a_d, n);
    k_edge<2, 2><<<egrid, 256, 0, stream>>>(rowinfo, src_sorted, h16a, h16b, a_s, a_d, b2, nullptr, bufB, n, 0.2f);

    // ---- layer 3 ----
    k_transform<1><<<tgrid, 256, 0, stream>>>(bufB, W3, as3, ad3, h16a, h16b, a_s, a_d, n);
    k_edge<1, 0><<<egrid, 256, 0, stream>>>(rowinfo, src_sorted, h16a, h16b, a_s, a_d, b3, nullptr, out, n, 0.2f);
}

// Round 4
// 423.108 us; speedup vs baseline: 1.0217x; 1.0217x over previous
//
#include <hip/hip_runtime.h>
#include <hip/hip_bf16.h>
#include <hip/hip_fp16.h>

// ---------------------------------------------------------------------------
// EnhancedRGCN (3-layer GAT), N=100000 nodes, E=3200000 edges, D=32.
// CSR-by-dst via FIXED-CAPACITY bucket binning (bucket = dst>>7, 128 nodes,
// CAPB=6144 slots). R13: k_bin LDS-staged bucket-grouped run writeback,
// exact-count reservations, relative cursors (memset init).
// R16: k_edge reverted to R13 (R14 wide-iter and R15 head-split both
// regressed a latency-bound interior; R15 proved gather traffic is not the
// bound: FETCH 122->33MB yet dur 47->78us). k_transform rewritten: W row o
// lives in 32 VGPRs per thread (o is fixed per lane; 8x float4 of L2-hot
// 4KB), x read as 8x ds_read_b128 broadcasts -> LDS ops/thread ~64 -> 8.
// Old version was LDS-issue-bound (~30-40us/dispatch, hidden under the
// top-5 cutoff); predicted ~10us. No segment-max; no float atomics.
// ---------------------------------------------------------------------------

#define NPB  128    // nodes per bucket (dst>>7)
#define CAPB 6144   // slots per bucket (exact mean ~4092, >30 sigma room)
#define PAD_SENTINEL 0xFFFFFFFFu

// ---------------- pass 1: bin edges into fixed bucket regions --------------
// LDS-staged: histogram -> (scan || global reservations) -> LDS scatter ->
// per-bucket coalesced run writeback. bucket_cursor[b] is RELATIVE (starts 0).
__global__ void __launch_bounds__(1024)
k_bin(const int* __restrict__ src, const int* __restrict__ dst,
      int* __restrict__ bucket_cursor, unsigned int* __restrict__ pairs,
      int e, int nb) {
    __shared__ int h[1024];                 // per-bucket count (this block)
    __shared__ int bs[1024];                // block-local exclusive base
    __shared__ int cb[1024];                // global (relative) reservation
    __shared__ unsigned int stage[8192];    // bucket-grouped staged pairs
    int t = threadIdx.x;
    h[t] = 0;
    __syncthreads();
    int e4 = e >> 2;
    int base4 = blockIdx.x * 2048;          // 1024 threads x 2 int4 each
    int boff[8];                            // (bucket<<16) | rank, or -1
    unsigned int pk[8];
#pragma unroll
    for (int k = 0; k < 2; k++) {
        int i4 = base4 + k * 1024 + t;
        if (i4 < e4) {
            int4 dv = ((const int4*)dst)[i4];
            int4 sv = ((const int4*)src)[i4];
            const int* dd = (const int*)&dv;
            const int* ss = (const int*)&sv;
#pragma unroll
            for (int j = 0; j < 4; j++) {
                int q = 4 * k + j;
                int d = dd[j];
                int b = d >> 7;
                pk[q] = ((unsigned int)ss[j] << 7) | (unsigned int)(d & 127);
                int off = atomicAdd(&h[b], 1);
                boff[q] = (b << 16) | off;
            }
        } else {
#pragma unroll
            for (int j = 0; j < 4; j++) boff[4 * k + j] = -1;
        }
    }
    __syncthreads();
    // global reservations (threads 128..128+nb) overlap the scan (wave 0):
    // both only read h[]; atomic latency hides under the shfl scan.
    if (t >= 128 && t - 128 < nb) {
        int b = t - 128;
        int c = h[b];
        cb[b] = c ? atomicAdd(&bucket_cursor[b], c) : 0;
    }
    if (t < 64) {                           // wave 0: scan 1024 bins (16/lane)
        int sum = 0;
#pragma unroll
        for (int j = 0; j < 16; j++) sum += h[t * 16 + j];
        int run = sum;
#pragma unroll
        for (int off = 1; off < 64; off <<= 1) {
            int v = __shfl_up(run, off, 64);
            if (t >= off) run += v;
        }
        int base = run - sum;               // exclusive
#pragma unroll
        for (int j = 0; j < 16; j++) {
            int b = t * 16 + j;
            bs[b] = base;
            base += h[b];
        }
    }
    __syncthreads();
#pragma unroll
    for (int q = 0; q < 8; q++) {           // scatter into bucket-grouped LDS
        if (boff[q] >= 0) {
            int b = boff[q] >> 16;
            stage[bs[b] + (boff[q] & 0xFFFF)] = pk[q];
        }
    }
    __syncthreads();
    // coalesced run writeback: wave w handles buckets w, w+16, ...
    int wv = t >> 6, ln = t & 63;
    for (int b = wv; b < nb; b += 16) {
        int c = h[b];
        if (c == 0) continue;
        int gb = cb[b];
        int room = CAPB - gb;               // overflow guard (relative cursor)
        if (c > room) c = (room > 0) ? room : 0;
        unsigned int* dp = pairs + (size_t)b * CAPB + gb;
        const unsigned int* sp = stage + bs[b];
        for (int o = ln; o < c; o += 64) dp[o] = sp[o];
    }
    if (blockIdx.x == 0 && t < (e & 3)) {   // tail (e not multiple of 4)
        int i = (e & ~3) + t;
        int d = dst[i];
        int b = d >> 7;
        int r = atomicAdd(&bucket_cursor[b], 1);
        if (r < CAPB)
            pairs[(size_t)b * CAPB + r] =
                ((unsigned int)src[i] << 7) | (unsigned int)(d & 127);
    }
}

// ---------------- pass 2: per-bucket LDS sort -> rowinfo + src_sorted ------
__global__ void __launch_bounds__(512)
k_bucket_sort(const unsigned int* __restrict__ pairs,
              const int* __restrict__ bucket_cursor,
              int2* __restrict__ rowinfo, int* __restrict__ src_sorted,
              int n) {
    __shared__ int cnt[NPB];
    __shared__ int cur[NPB];
    __shared__ int total;
    __shared__ unsigned int lp[CAPB];
    __shared__ int op[CAPB];
    int b = blockIdx.x;
    int t = threadIdx.x;
    int bbase = b * CAPB;
    int m = bucket_cursor[b];               // relative cursor = exact count
    if (m > CAPB) m = CAPB;
    if (t < NPB) cnt[t] = 0;
    __syncthreads();
    for (int cb = 0; cb < m; cb += 4096) {
        unsigned int pv[8];
#pragma unroll
        for (int u = 0; u < 8; u++) {
            int i = cb + u * 512 + t;
            pv[u] = (i < m) ? pairs[bbase + i] : PAD_SENTINEL;
        }
#pragma unroll
        for (int u = 0; u < 8; u++) {
            int i = cb + u * 512 + t;
            if (i < m) lp[i] = pv[u];
            if (pv[u] != PAD_SENTINEL) atomicAdd(&cnt[pv[u] & 127], 1);
        }
    }
    __syncthreads();
    if (t < 64) {                       // wave 0 only: shfl scan over 128 bins
        int c0 = cnt[2 * t];
        int c1 = cnt[2 * t + 1];
        int sum = c0 + c1;
        int run = sum;
#pragma unroll
        for (int off = 1; off < 64; off <<= 1) {
            int v = __shfl_up(run, off, 64);
            if (t >= off) run += v;
        }
        int ex = run - sum;             // exclusive
        cur[2 * t] = ex;
        cur[2 * t + 1] = ex + c0;
        int node = b * NPB + 2 * t;
        if (node < n) rowinfo[node] = make_int2(bbase + ex, c0);
        if (node + 1 < n) rowinfo[node + 1] = make_int2(bbase + ex + c0, c1);
        if (t == 63) total = run;       // dense entry count
    }
    __syncthreads();
    for (int cb = 0; cb < m; cb += 4096) {
        unsigned int pv[8];
        int of[8];
#pragma unroll
        for (int u = 0; u < 8; u++) {
            int i = cb + u * 512 + t;
            pv[u] = (i < m) ? lp[i] : PAD_SENTINEL;
        }
#pragma unroll
        for (int u = 0; u < 8; u++)
            if (pv[u] != PAD_SENTINEL) of[u] = atomicAdd(&cur[pv[u] & 127], 1);
#pragma unroll
        for (int u = 0; u < 8; u++)
            if (pv[u] != PAD_SENTINEL) op[of[u]] = (int)(pv[u] >> 7);
    }
    __syncthreads();
    int nt4 = (total + 3) >> 2;
    int4* dst4 = (int4*)(src_sorted + bbase);
    const int4* src4 = (const int4*)op;
    for (int i = t; i < nt4; i += 512) dst4[i] = src4[i];
}

// ---------------- per-layer dense transform ----------------
// R16: W row o held in 32 VGPRs (o fixed per thread; 4KB L2-hot), x via
// 8x ds_read_b128 broadcast. Old version issued ~64 scalar LDS reads per
// thread (LDS-issue-bound, ~30-40us); this issues 8.
template <int H>
__global__ void k_transform(const float* __restrict__ in, const float* __restrict__ W,
                            const float* __restrict__ att_s, const float* __restrict__ att_d,
                            __half* __restrict__ h16, float* __restrict__ a_s,
                            float* __restrict__ a_d, int n) {
    constexpr int C = 32 / H;
    __shared__ float xs[8][32];
    int t = threadIdx.x;
    int nl = t >> 5, o = t & 31;
    float w[32];
#pragma unroll
    for (int j = 0; j < 8; j++) {
        float4 wv = ((const float4*)W)[o * 8 + j];
        w[4 * j]     = wv.x;
        w[4 * j + 1] = wv.y;
        w[4 * j + 2] = wv.z;
        w[4 * j + 3] = wv.w;
    }
    int node = blockIdx.x * 8 + nl;
    xs[nl][o] = (node < n) ? in[node * 32 + o] : 0.f;
    __syncthreads();
    float acc = 0.f;
#pragma unroll
    for (int j = 0; j < 8; j++) {
        float4 xq = *(const float4*)(&xs[nl][4 * j]);
        acc = fmaf(xq.x, w[4 * j], acc);
        acc = fmaf(xq.y, w[4 * j + 1], acc);
        acc = fmaf(xq.z, w[4 * j + 2], acc);
        acc = fmaf(xq.w, w[4 * j + 3], acc);
    }
    if (node < n) {
        h16[node * 32 + o] = __float2half_rn(acc);
        float vs = acc * att_s[o];
        float vd = acc * att_d[o];
#pragma unroll
        for (int m = C / 2; m >= 1; m >>= 1) {
            vs += __shfl_xor(vs, m, 64);
            vd += __shfl_xor(vd, m, 64);
        }
        if ((o % C) == 0) {
            int hh = o / C;
            a_s[node * H + hh] = vs;
            a_d[node * H + hh] = vd;
        }
    }
}

// ---------------- per-layer fused edge softmax + aggregation ----------------
// TWO NODES PER WAVE: half-wave (32 lanes) per node. 8 nodes per 256-block.
// Pass A: half-wave lane-per-edge (stride 32), stash (s,ex) per head in LDS
//         zero-padded to mult of 16; denominator partials.
// Pass B: 2 slots x 16 channel-lanes per node; 16 edges/node/iteration via
//         4 ds_read_b128 + 8 half2 gathers in flight + 16 fma_mix.
// Denominator: 5-level half-wave butterfly after pass B; acc: 1 level.
// EPI: 0 = bias only (layer3), 1 = layer1 epilogue, 2 = elu+clip (layer2).
template <int H, int EPI>
__global__ void k_edge(const int2* __restrict__ rowinfo, const int* __restrict__ src_sorted,
                       const __half* __restrict__ h16,
                       const float* __restrict__ a_s, const float* __restrict__ a_d,
                       const float* __restrict__ bias, const float* __restrict__ ea,
                       float* __restrict__ out, int n, float slope) {
    constexpr int CAP = 128;                  // entries per node per head
    constexpr int RSTR = 2 * CAP + 16;        // region stride in ints (+64B pad)
    __shared__ int lds_raw[8][H][RSTR];
    int nw = threadIdx.x >> 5;                // node slot 0..7
    int hl = threadIdx.x & 31;                // half-wave lane
    int node = blockIdx.x * 8 + nw;
    if (node >= n) return;
    int2 bi = rowinfo[node];
    int beg = bi.x, deg = bi.y;
    int padB = (deg + 15) & ~15;

    float ad[H];
#pragma unroll
    for (int hh = 0; hh < H; hh++) ad[hh] = a_d[node * H + hh];

    // ---- pass A: stash (s, ex) per head + denominator partials ----
    float ds[H];
#pragma unroll
    for (int hh = 0; hh < H; hh++) ds[hh] = 0.f;
    bool fast = (padB <= CAP);
    if (fast) {
        for (int idx = hl; idx < padB; idx += 32) {
            if (idx < deg) {
                int s = src_sorted[beg + idx];
                if (H == 2) {
                    float2 as2 = *(const float2*)((const char*)a_s + (unsigned)(s << 3));
                    float l0 = as2.x + ad[0]; l0 = fmaxf(l0, l0 * slope);
                    float l1 = as2.y + ad[1]; l1 = fmaxf(l1, l1 * slope);
                    float e0 = __expf(l0), e1 = __expf(l1);
                    ds[0] += e0; ds[1] += e1;
                    ((int2*)lds_raw[nw][0])[idx] = make_int2(s, __float_as_int(e0));
                    ((int2*)lds_raw[nw][H - 1])[idx] = make_int2(s, __float_as_int(e1));
                } else {
                    float l0 = a_s[s] + ad[0]; l0 = fmaxf(l0, l0 * slope);
                    float e0 = __expf(l0);
                    ds[0] += e0;
                    ((int2*)lds_raw[nw][0])[idx] = make_int2(s, __float_as_int(e0));
                }
            } else {
#pragma unroll
                for (int hh = 0; hh < H; hh++)
                    ((int2*)lds_raw[nw][hh])[idx] = make_int2(0, 0);
            }
        }
    } else {
        for (int idx = hl; idx < deg; idx += 32) {
            int s = src_sorted[beg + idx];
            if (H == 2) {
                float2 as2 = *(const float2*)((const char*)a_s + (unsigned)(s << 3));
                float l0 = as2.x + ad[0]; l0 = fmaxf(l0, l0 * slope);
                float l1 = as2.y + ad[1]; l1 = fmaxf(l1, l1 * slope);
                ds[0] += __expf(l0); ds[1] += __expf(l1);
            } else {
                float l0 = a_s[s] + ad[0]; l0 = fmaxf(l0, l0 * slope);
                ds[0] += __expf(l0);
            }
        }
    }

    // ---- pass B: 2 slots x 16 lanes per node; 16 edges/node/iteration ----
    int e2 = hl >> 4;          // slot 0/1
    int l16 = hl & 15;         // channel pair 0..15
    int hd = (H == 2) ? (l16 >> 3) : 0;
    int co = l16 << 2;
    float adh = ad[hd];
    float acc0 = 0.f, acc1 = 0.f;
    const char* hbase = (const char*)h16;
    const int* lb = &lds_raw[nw][hd][e2 * 4];   // entry offset 2*e2

    if (fast) {
        // slot e2 covers entries base + {0,1,4,5,8,9,12,13} + 2*e2
        for (int base = 0; base < padB; base += 16) {
            int4 qa = *(const int4*)(lb + base * 2);
            int4 qb = *(const int4*)(lb + base * 2 + 8);
            int4 qc = *(const int4*)(lb + base * 2 + 16);
            int4 qd = *(const int4*)(lb + base * 2 + 24);
            __half2 h0 = *(const __half2*)(hbase + (unsigned)((qa.x << 6) + co));
            __half2 h1 = *(const __half2*)(hbase + (unsigned)((qa.z << 6) + co));
            __half2 h2 = *(const __half2*)(hbase + (unsigned)((qb.x << 6) + co));
            __half2 h3 = *(const __half2*)(hbase + (unsigned)((qb.z << 6) + co));
            __half2 h4 = *(const __half2*)(hbase + (unsigned)((qc.x << 6) + co));
            __half2 h5 = *(const __half2*)(hbase + (unsigned)((qc.z << 6) + co));
            __half2 h6 = *(const __half2*)(hbase + (unsigned)((qd.x << 6) + co));
            __half2 h7 = *(const __half2*)(hbase + (unsigned)((qd.z << 6) + co));
            float xa0 = __int_as_float(qa.y), xa1 = __int_as_float(qa.w);
            float xb0 = __int_as_float(qb.y), xb1 = __int_as_float(qb.w);
            float xc0 = __int_as_float(qc.y), xc1 = __int_as_float(qc.w);
            float xd0 = __int_as_float(qd.y), xd1 = __int_as_float(qd.w);
            acc0 = fmaf(xa0, __half2float(__low2half(h0)), acc0);
            acc1 = fmaf(xa0, __half2float(__high2half(h0)), acc1);
            acc0 = fmaf(xa1, __half2float(__low2half(h1)), acc0);
            acc1 = fmaf(xa1, __half2float(__high2half(h1)), acc1);
            acc0 = fmaf(xb0, __half2float(__low2half(h2)), acc0);
            acc1 = fmaf(xb0, __half2float(__high2half(h2)), acc1);
            acc0 = fmaf(xb1, __half2float(__low2half(h3)), acc0);
            acc1 = fmaf(xb1, __half2float(__high2half(h3)), acc1);
            acc0 = fmaf(xc0, __half2float(__low2half(h4)), acc0);
            acc1 = fmaf(xc0, __half2float(__high2half(h4)), acc1);
            acc0 = fmaf(xc1, __half2float(__low2half(h5)), acc0);
            acc1 = fmaf(xc1, __half2float(__high2half(h5)), acc1);
            acc0 = fmaf(xd0, __half2float(__low2half(h6)), acc0);
            acc1 = fmaf(xd0, __half2float(__high2half(h6)), acc1);
            acc0 = fmaf(xd1, __half2float(__low2half(h7)), acc0);
            acc1 = fmaf(xd1, __half2float(__high2half(h7)), acc1);
        }
    } else {
        for (int base = 0; base < deg; base += 16) {
#pragma unroll
            for (int u = 0; u < 8; u++) {
                int idx = base + u * 2 + e2;
                int s = 0;
                float ex = 0.f;
                if (idx < deg) {
                    s = src_sorted[beg + idx];
                    float l = a_s[s * H + hd] + adh;
                    l = fmaxf(l, l * slope);
                    ex = __expf(l);
                }
                __half2 hv = *(const __half2*)(hbase + (unsigned)((s << 6) + co));
                acc0 = fmaf(ex, __half2float(__low2half(hv)), acc0);
                acc1 = fmaf(ex, __half2float(__high2half(hv)), acc1);
            }
        }
    }

    // ---- denominator reduction (5-level half-wave butterfly, deferred) ----
#pragma unroll
    for (int hh = 0; hh < H; hh++) {
        float v = ds[hh];
#pragma unroll
        for (int m = 16; m >= 1; m >>= 1) v += __shfl_xor(v, m, 64);
        ds[hh] = 1.f / (v + 1e-16f);
    }

    // ---- reduce accs across the 2 slots (1 level) ----
    acc0 += __shfl_xor(acc0, 16, 64);
    acc1 += __shfl_xor(acc1, 16, 64);

    if (l16 == hl) {           // hl < 16: slot-0 lanes hold the result
        float invd = ds[hd];
        float2 bv = *(const float2*)(bias + l16 * 2);
        float v0 = fmaf(acc0, invd, bv.x);
        float v1 = fmaf(acc1, invd, bv.y);
        if (EPI == 1) {
            float s0 = tanhf(ea[0]);
            if (s0 < 0.1f) s0 = 1.0f;
            s0 *= 1.05f;
            v0 *= s0; v1 *= s0;
            v0 = (v0 > 0.f) ? v0 : expm1f(v0);
            v1 = (v1 > 0.f) ? v1 : expm1f(v1);
            v0 = fminf(3.f, fmaxf(-3.f, v0));
            v1 = fminf(3.f, fmaxf(-3.f, v1));
        } else if (EPI == 2) {
            v0 = (v0 > 0.f) ? v0 : expm1f(v0);
            v1 = (v1 > 0.f) ? v1 : expm1f(v1);
            v0 = fminf(3.f, fmaxf(-3.f, v0));
            v1 = fminf(3.f, fmaxf(-3.f, v1));
        }
        *(float2*)(out + (size_t)node * 32 + l16 * 2) = make_float2(v0, v1);
    }
}

// ---------------------------------------------------------------------------
extern "C" void kernel_launch(void* const* d_in, const int* in_sizes, int n_in,
                              void* d_out, int out_size, void* d_ws, size_t ws_size,
                              hipStream_t stream) {
    const float* x   = (const float*)d_in[0];
    const int*   ei  = (const int*)d_in[1];
    const float* W1  = (const float*)d_in[2];
    const float* as1 = (const float*)d_in[3];
    const float* ad1 = (const float*)d_in[4];
    const float* b1  = (const float*)d_in[5];
    const float* ea1 = (const float*)d_in[6];
    const float* W2  = (const float*)d_in[7];
    const float* as2 = (const float*)d_in[8];
    const float* ad2 = (const float*)d_in[9];
    const float* b2  = (const float*)d_in[10];
    const float* W3  = (const float*)d_in[11];
    const float* as3 = (const float*)d_in[12];
    const float* ad3 = (const float*)d_in[13];
    const float* b3  = (const float*)d_in[14];
    float* out = (float*)d_out;

    const int n = in_sizes[0] / 32;   // 100000
    const int e = in_sizes[1] / 2;    // 3200000
    const int* src = ei;
    const int* dst = ei + e;
    const int nb = (n + NPB - 1) / NPB;   // 782 buckets

    char* w = (char*)d_ws;
    auto alloc = [&](size_t bytes) -> void* {
        void* p = (void*)w;
        w += (bytes + 255) & ~(size_t)255;
        return p;
    };
    __half* h16     = (__half*)alloc((size_t)n * 32 * 2);
    float* a_s      = (float*)alloc((size_t)n * 2 * 4);
    float* a_d      = (float*)alloc((size_t)n * 2 * 4);
    float* bufA     = (float*)alloc((size_t)n * 32 * 4);
    float* bufB     = (float*)alloc((size_t)n * 32 * 4);
    int2* rowinfo   = (int2*)alloc((size_t)n * 8);
    int* bucket_cur = (int*)alloc((size_t)(nb + 1) * 4);
    int* src_sorted = (int*)alloc((size_t)nb * CAPB * 4);
    unsigned int* pairs = (unsigned int*)bufA;   // aliased; consumed pre-layer1

    // ---- build CSR by dst (LDS-staged bucket binning, exact counts) ----
    hipMemsetAsync(bucket_cur, 0, (size_t)nb * 4, stream);   // relative cursors
    int e4 = e >> 2;
    k_bin<<<(e4 + 2047) / 2048, 1024, 0, stream>>>(src, dst, bucket_cur, pairs, e, nb);
    k_bucket_sort<<<nb, 512, 0, stream>>>(pairs, bucket_cur, rowinfo, src_sorted, n);

    const int tgrid = (n + 7) / 8;
    const int egrid = (n + 7) / 8;

    // ---- layer 1 ----
    k_transform<2><<<tgrid, 256, 0, stream>>>(x, W1, as1, ad1, h16, a_s, a_d, n);
    k_edge<2, 1><<<egrid, 256, 0, stream>>>(rowinfo, src_sorted, h16, a_s, a_d, b1, ea1, bufA, n, 0.01f);

    // ---- layer 2 ----
    k_transform<2><<<tgrid, 256, 0, stream>>>(bufA, W2, as2, ad2, h16, a_s, a_d, n);
    k_edge<2, 2><<<egrid, 256, 0, stream>>>(rowinfo, src_sorted, h16, a_s, a_d, b2, nullptr, bufB, n, 0.2f);

    // ---- layer 3 ----
    k_transform<1><<<tgrid, 256, 0, stream>>>(bufB, W3, as3, ad3, h16, a_s, a_d, n);
    k_edge<1, 0><<<egrid, 256, 0, stream>>>(rowinfo, src_sorted, h16, a_s, a_d, b3, nullptr, out, n, 0.2f);
}

// Round 5
// 368.086 us; speedup vs baseline: 1.1745x; 1.1495x over previous
//
#include <hip/hip_runtime.h>
#include <hip/hip_bf16.h>
#include <hip/hip_fp16.h>

// ---------------------------------------------------------------------------
// EnhancedRGCN (3-layer GAT), N=100000 nodes, E=3200000 edges, D=32.
// CSR-by-dst via FIXED-CAPACITY bucket binning (bucket = dst>>7, 128 nodes,
// CAPB=6144 slots). R13: k_bin LDS-staged bucket-grouped run writeback.
// R17: k_transform amortized — 64 nodes/block (grid 1563), each thread owns
// channel o and computes 8 nodes. W row pulled once into 32 VGPRs via 32
// conflict-free ds_read_b32 from padded LDS (bank=(o+k)%32, distinct/lane);
// x rows read as 8x ds_read_b128 half-wave broadcasts per node. Per-output
// LDS issues 64 -> 12; model: ~10us/dispatch (was 26 old / 53 R16 — R16's
// per-lane stride-128B global W gather was the regression: 32 cache lines
// per dwordx4, VALUBusy 12%). k_edge byte-identical to R13 (47.4us control).
// No segment-max (shift-invariant softmax, bounded logits); no float atomics.
// ---------------------------------------------------------------------------

#define NPB  128    // nodes per bucket (dst>>7)
#define CAPB 6144   // slots per bucket (exact mean ~4092, >30 sigma room)
#define PAD_SENTINEL 0xFFFFFFFFu

// ---------------- pass 1: bin edges into fixed bucket regions --------------
// LDS-staged: histogram -> (scan || global reservations) -> LDS scatter ->
// per-bucket coalesced run writeback. bucket_cursor[b] is RELATIVE (starts 0).
__global__ void __launch_bounds__(1024)
k_bin(const int* __restrict__ src, const int* __restrict__ dst,
      int* __restrict__ bucket_cursor, unsigned int* __restrict__ pairs,
      int e, int nb) {
    __shared__ int h[1024];                 // per-bucket count (this block)
    __shared__ int bs[1024];                // block-local exclusive base
    __shared__ int cb[1024];                // global (relative) reservation
    __shared__ unsigned int stage[8192];    // bucket-grouped staged pairs
    int t = threadIdx.x;
    h[t] = 0;
    __syncthreads();
    int e4 = e >> 2;
    int base4 = blockIdx.x * 2048;          // 1024 threads x 2 int4 each
    int boff[8];                            // (bucket<<16) | rank, or -1
    unsigned int pk[8];
#pragma unroll
    for (int k = 0; k < 2; k++) {
        int i4 = base4 + k * 1024 + t;
        if (i4 < e4) {
            int4 dv = ((const int4*)dst)[i4];
            int4 sv = ((const int4*)src)[i4];
            const int* dd = (const int*)&dv;
            const int* ss = (const int*)&sv;
#pragma unroll
            for (int j = 0; j < 4; j++) {
                int q = 4 * k + j;
                int d = dd[j];
                int b = d >> 7;
                pk[q] = ((unsigned int)ss[j] << 7) | (unsigned int)(d & 127);
                int off = atomicAdd(&h[b], 1);
                boff[q] = (b << 16) | off;
            }
        } else {
#pragma unroll
            for (int j = 0; j < 4; j++) boff[4 * k + j] = -1;
        }
    }
    __syncthreads();
    // global reservations (threads 128..128+nb) overlap the scan (wave 0):
    // both only read h[]; atomic latency hides under the shfl scan.
    if (t >= 128 && t - 128 < nb) {
        int b = t - 128;
        int c = h[b];
        cb[b] = c ? atomicAdd(&bucket_cursor[b], c) : 0;
    }
    if (t < 64) {                           // wave 0: scan 1024 bins (16/lane)
        int sum = 0;
#pragma unroll
        for (int j = 0; j < 16; j++) sum += h[t * 16 + j];
        int run = sum;
#pragma unroll
        for (int off = 1; off < 64; off <<= 1) {
            int v = __shfl_up(run, off, 64);
            if (t >= off) run += v;
        }
        int base = run - sum;               // exclusive
#pragma unroll
        for (int j = 0; j < 16; j++) {
            int b = t * 16 + j;
            bs[b] = base;
            base += h[b];
        }
    }
    __syncthreads();
#pragma unroll
    for (int q = 0; q < 8; q++) {           // scatter into bucket-grouped LDS
        if (boff[q] >= 0) {
            int b = boff[q] >> 16;
            stage[bs[b] + (boff[q] & 0xFFFF)] = pk[q];
        }
    }
    __syncthreads();
    // coalesced run writeback: wave w handles buckets w, w+16, ...
    int wv = t >> 6, ln = t & 63;
    for (int b = wv; b < nb; b += 16) {
        int c = h[b];
        if (c == 0) continue;
        int gb = cb[b];
        int room = CAPB - gb;               // overflow guard (relative cursor)
        if (c > room) c = (room > 0) ? room : 0;
        unsigned int* dp = pairs + (size_t)b * CAPB + gb;
        const unsigned int* sp = stage + bs[b];
        for (int o = ln; o < c; o += 64) dp[o] = sp[o];
    }
    if (blockIdx.x == 0 && t < (e & 3)) {   // tail (e not multiple of 4)
        int i = (e & ~3) + t;
        int d = dst[i];
        int b = d >> 7;
        int r = atomicAdd(&bucket_cursor[b], 1);
        if (r < CAPB)
            pairs[(size_t)b * CAPB + r] =
                ((unsigned int)src[i] << 7) | (unsigned int)(d & 127);
    }
}

// ---------------- pass 2: per-bucket LDS sort -> rowinfo + src_sorted ------
__global__ void __launch_bounds__(512)
k_bucket_sort(const unsigned int* __restrict__ pairs,
              const int* __restrict__ bucket_cursor,
              int2* __restrict__ rowinfo, int* __restrict__ src_sorted,
              int n) {
    __shared__ int cnt[NPB];
    __shared__ int cur[NPB];
    __shared__ int total;
    __shared__ unsigned int lp[CAPB];
    __shared__ int op[CAPB];
    int b = blockIdx.x;
    int t = threadIdx.x;
    int bbase = b * CAPB;
    int m = bucket_cursor[b];               // relative cursor = exact count
    if (m > CAPB) m = CAPB;
    if (t < NPB) cnt[t] = 0;
    __syncthreads();
    for (int cb = 0; cb < m; cb += 4096) {
        unsigned int pv[8];
#pragma unroll
        for (int u = 0; u < 8; u++) {
            int i = cb + u * 512 + t;
            pv[u] = (i < m) ? pairs[bbase + i] : PAD_SENTINEL;
        }
#pragma unroll
        for (int u = 0; u < 8; u++) {
            int i = cb + u * 512 + t;
            if (i < m) lp[i] = pv[u];
            if (pv[u] != PAD_SENTINEL) atomicAdd(&cnt[pv[u] & 127], 1);
        }
    }
    __syncthreads();
    if (t < 64) {                       // wave 0 only: shfl scan over 128 bins
        int c0 = cnt[2 * t];
        int c1 = cnt[2 * t + 1];
        int sum = c0 + c1;
        int run = sum;
#pragma unroll
        for (int off = 1; off < 64; off <<= 1) {
            int v = __shfl_up(run, off, 64);
            if (t >= off) run += v;
        }
        int ex = run - sum;             // exclusive
        cur[2 * t] = ex;
        cur[2 * t + 1] = ex + c0;
        int node = b * NPB + 2 * t;
        if (node < n) rowinfo[node] = make_int2(bbase + ex, c0);
        if (node + 1 < n) rowinfo[node + 1] = make_int2(bbase + ex + c0, c1);
        if (t == 63) total = run;       // dense entry count
    }
    __syncthreads();
    for (int cb = 0; cb < m; cb += 4096) {
        unsigned int pv[8];
        int of[8];
#pragma unroll
        for (int u = 0; u < 8; u++) {
            int i = cb + u * 512 + t;
            pv[u] = (i < m) ? lp[i] : PAD_SENTINEL;
        }
#pragma unroll
        for (int u = 0; u < 8; u++)
            if (pv[u] != PAD_SENTINEL) of[u] = atomicAdd(&cur[pv[u] & 127], 1);
#pragma unroll
        for (int u = 0; u < 8; u++)
            if (pv[u] != PAD_SENTINEL) op[of[u]] = (int)(pv[u] >> 7);
    }
    __syncthreads();
    int nt4 = (total + 3) >> 2;
    int4* dst4 = (int4*)(src_sorted + bbase);
    const int4* src4 = (const int4*)op;
    for (int i = t; i < nt4; i += 512) dst4[i] = src4[i];
}

// ---------------- per-layer dense transform ----------------
// R17: 64 nodes/block, 8 outputs/thread. W row in 32 VGPRs via conflict-free
// scalar LDS reads (padded [33] stride, bank=(o+k)%32); x via b128 broadcast.
template <int H>
__global__ void __launch_bounds__(256)
k_transform(const float* __restrict__ in, const float* __restrict__ W,
            const float* __restrict__ att_s, const float* __restrict__ att_d,
            __half* __restrict__ h16, float* __restrict__ a_s,
            float* __restrict__ a_d, int n) {
    constexpr int C = 32 / H;
    __shared__ float Wl[32][33];
    __shared__ float xs[64][32];
    int t = threadIdx.x;
    for (int i = t; i < 1024; i += 256) Wl[i >> 5][i & 31] = W[i];
    {   // coalesced x stage: 8 consecutive floats per thread
        int gi = blockIdx.x * 2048 + t * 8;
        int lim = n * 32;
        float4 v0 = make_float4(0.f, 0.f, 0.f, 0.f), v1 = v0;
        if (gi + 3 < lim) v0 = *(const float4*)(in + gi);
        if (gi + 7 < lim) v1 = *(const float4*)(in + gi + 4);
        *(float4*)(&xs[0][0] + t * 8) = v0;
        *(float4*)(&xs[0][0] + t * 8 + 4) = v1;
    }
    __syncthreads();
    int nl = t >> 5, o = t & 31;
    float w[32];
#pragma unroll
    for (int k = 0; k < 32; k++) w[k] = Wl[o][k];   // conflict-free per lane
    float ats = att_s[o], atd = att_d[o];
    float acc[8];
#pragma unroll
    for (int r = 0; r < 8; r++) {
        const float* xr = xs[nl * 8 + r];
        float a = 0.f;
#pragma unroll
        for (int j = 0; j < 8; j++) {
            float4 xq = *(const float4*)(xr + 4 * j);   // half-wave broadcast
            a = fmaf(xq.x, w[4 * j], a);
            a = fmaf(xq.y, w[4 * j + 1], a);
            a = fmaf(xq.z, w[4 * j + 2], a);
            a = fmaf(xq.w, w[4 * j + 3], a);
        }
        acc[r] = a;
    }
    int nodeBase = blockIdx.x * 64 + nl * 8;
#pragma unroll
    for (int r = 0; r < 8; r++) {
        int node = nodeBase + r;
        float a = acc[r];
        float vs = a * ats;
        float vd = a * atd;
#pragma unroll
        for (int m = C / 2; m >= 1; m >>= 1) {
            vs += __shfl_xor(vs, m, 64);
            vd += __shfl_xor(vd, m, 64);
        }
        if (node < n) {
            h16[node * 32 + o] = __float2half_rn(a);
            if ((o % C) == 0) {
                int hh = o / C;
                a_s[node * H + hh] = vs;
                a_d[node * H + hh] = vd;
            }
        }
    }
}

// ---------------- per-layer fused edge softmax + aggregation ----------------
// TWO NODES PER WAVE: half-wave (32 lanes) per node. 8 nodes per 256-block.
// Pass A: half-wave lane-per-edge (stride 32), stash (s,ex) per head in LDS
//         zero-padded to mult of 16; denominator partials.
// Pass B: 2 slots x 16 channel-lanes per node; 16 edges/node/iteration via
//         4 ds_read_b128 + 8 half2 gathers in flight + 16 fma_mix.
// Denominator: 5-level half-wave butterfly after pass B; acc: 1 level.
// EPI: 0 = bias only (layer3), 1 = layer1 epilogue, 2 = elu+clip (layer2).
template <int H, int EPI>
__global__ void k_edge(const int2* __restrict__ rowinfo, const int* __restrict__ src_sorted,
                       const __half* __restrict__ h16,
                       const float* __restrict__ a_s, const float* __restrict__ a_d,
                       const float* __restrict__ bias, const float* __restrict__ ea,
                       float* __restrict__ out, int n, float slope) {
    constexpr int CAP = 128;                  // entries per node per head
    constexpr int RSTR = 2 * CAP + 16;        // region stride in ints (+64B pad)
    __shared__ int lds_raw[8][H][RSTR];
    int nw = threadIdx.x >> 5;                // node slot 0..7
    int hl = threadIdx.x & 31;                // half-wave lane
    int node = blockIdx.x * 8 + nw;
    if (node >= n) return;
    int2 bi = rowinfo[node];
    int beg = bi.x, deg = bi.y;
    int padB = (deg + 15) & ~15;

    float ad[H];
#pragma unroll
    for (int hh = 0; hh < H; hh++) ad[hh] = a_d[node * H + hh];

    // ---- pass A: stash (s, ex) per head + denominator partials ----
    float ds[H];
#pragma unroll
    for (int hh = 0; hh < H; hh++) ds[hh] = 0.f;
    bool fast = (padB <= CAP);
    if (fast) {
        for (int idx = hl; idx < padB; idx += 32) {
            if (idx < deg) {
                int s = src_sorted[beg + idx];
                if (H == 2) {
                    float2 as2 = *(const float2*)((const char*)a_s + (unsigned)(s << 3));
                    float l0 = as2.x + ad[0]; l0 = fmaxf(l0, l0 * slope);
                    float l1 = as2.y + ad[1]; l1 = fmaxf(l1, l1 * slope);
                    float e0 = __expf(l0), e1 = __expf(l1);
                    ds[0] += e0; ds[1] += e1;
                    ((int2*)lds_raw[nw][0])[idx] = make_int2(s, __float_as_int(e0));
                    ((int2*)lds_raw[nw][H - 1])[idx] = make_int2(s, __float_as_int(e1));
                } else {
                    float l0 = a_s[s] + ad[0]; l0 = fmaxf(l0, l0 * slope);
                    float e0 = __expf(l0);
                    ds[0] += e0;
                    ((int2*)lds_raw[nw][0])[idx] = make_int2(s, __float_as_int(e0));
                }
            } else {
#pragma unroll
                for (int hh = 0; hh < H; hh++)
                    ((int2*)lds_raw[nw][hh])[idx] = make_int2(0, 0);
            }
        }
    } else {
        for (int idx = hl; idx < deg; idx += 32) {
            int s = src_sorted[beg + idx];
            if (H == 2) {
                float2 as2 = *(const float2*)((const char*)a_s + (unsigned)(s << 3));
                float l0 = as2.x + ad[0]; l0 = fmaxf(l0, l0 * slope);
                float l1 = as2.y + ad[1]; l1 = fmaxf(l1, l1 * slope);
                ds[0] += __expf(l0); ds[1] += __expf(l1);
            } else {
                float l0 = a_s[s] + ad[0]; l0 = fmaxf(l0, l0 * slope);
                ds[0] += __expf(l0);
            }
        }
    }

    // ---- pass B: 2 slots x 16 lanes per node; 16 edges/node/iteration ----
    int e2 = hl >> 4;          // slot 0/1
    int l16 = hl & 15;         // channel pair 0..15
    int hd = (H == 2) ? (l16 >> 3) : 0;
    int co = l16 << 2;
    float adh = ad[hd];
    float acc0 = 0.f, acc1 = 0.f;
    const char* hbase = (const char*)h16;
    const int* lb = &lds_raw[nw][hd][e2 * 4];   // entry offset 2*e2

    if (fast) {
        // slot e2 covers entries base + {0,1,4,5,8,9,12,13} + 2*e2
        for (int base = 0; base < padB; base += 16) {
            int4 qa = *(const int4*)(lb + base * 2);
            int4 qb = *(const int4*)(lb + base * 2 + 8);
            int4 qc = *(const int4*)(lb + base * 2 + 16);
            int4 qd = *(const int4*)(lb + base * 2 + 24);
            __half2 h0 = *(const __half2*)(hbase + (unsigned)((qa.x << 6) + co));
            __half2 h1 = *(const __half2*)(hbase + (unsigned)((qa.z << 6) + co));
            __half2 h2 = *(const __half2*)(hbase + (unsigned)((qb.x << 6) + co));
            __half2 h3 = *(const __half2*)(hbase + (unsigned)((qb.z << 6) + co));
            __half2 h4 = *(const __half2*)(hbase + (unsigned)((qc.x << 6) + co));
            __half2 h5 = *(const __half2*)(hbase + (unsigned)((qc.z << 6) + co));
            __half2 h6 = *(const __half2*)(hbase + (unsigned)((qd.x << 6) + co));
            __half2 h7 = *(const __half2*)(hbase + (unsigned)((qd.z << 6) + co));
            float xa0 = __int_as_float(qa.y), xa1 = __int_as_float(qa.w);
            float xb0 = __int_as_float(qb.y), xb1 = __int_as_float(qb.w);
            float xc0 = __int_as_float(qc.y), xc1 = __int_as_float(qc.w);
            float xd0 = __int_as_float(qd.y), xd1 = __int_as_float(qd.w);
            acc0 = fmaf(xa0, __half2float(__low2half(h0)), acc0);
            acc1 = fmaf(xa0, __half2float(__high2half(h0)), acc1);
            acc0 = fmaf(xa1, __half2float(__low2half(h1)), acc0);
            acc1 = fmaf(xa1, __half2float(__high2half(h1)), acc1);
            acc0 = fmaf(xb0, __half2float(__low2half(h2)), acc0);
            acc1 = fmaf(xb0, __half2float(__high2half(h2)), acc1);
            acc0 = fmaf(xb1, __half2float(__low2half(h3)), acc0);
            acc1 = fmaf(xb1, __half2float(__high2half(h3)), acc1);
            acc0 = fmaf(xc0, __half2float(__low2half(h4)), acc0);
            acc1 = fmaf(xc0, __half2float(__high2half(h4)), acc1);
            acc0 = fmaf(xc1, __half2float(__low2half(h5)), acc0);
            acc1 = fmaf(xc1, __half2float(__high2half(h5)), acc1);
            acc0 = fmaf(xd0, __half2float(__low2half(h6)), acc0);
            acc1 = fmaf(xd0, __half2float(__high2half(h6)), acc1);
            acc0 = fmaf(xd1, __half2float(__low2half(h7)), acc0);
            acc1 = fmaf(xd1, __half2float(__high2half(h7)), acc1);
        }
    } else {
        for (int base = 0; base < deg; base += 16) {
#pragma unroll
            for (int u = 0; u < 8; u++) {
                int idx = base + u * 2 + e2;
                int s = 0;
                float ex = 0.f;
                if (idx < deg) {
                    s = src_sorted[beg + idx];
                    float l = a_s[s * H + hd] + adh;
                    l = fmaxf(l, l * slope);
                    ex = __expf(l);
                }
                __half2 hv = *(const __half2*)(hbase + (unsigned)((s << 6) + co));
                acc0 = fmaf(ex, __half2float(__low2half(hv)), acc0);
                acc1 = fmaf(ex, __half2float(__high2half(hv)), acc1);
            }
        }
    }

    // ---- denominator reduction (5-level half-wave butterfly, deferred) ----
#pragma unroll
    for (int hh = 0; hh < H; hh++) {
        float v = ds[hh];
#pragma unroll
        for (int m = 16; m >= 1; m >>= 1) v += __shfl_xor(v, m, 64);
        ds[hh] = 1.f / (v + 1e-16f);
    }

    // ---- reduce accs across the 2 slots (1 level) ----
    acc0 += __shfl_xor(acc0, 16, 64);
    acc1 += __shfl_xor(acc1, 16, 64);

    if (l16 == hl) {           // hl < 16: slot-0 lanes hold the result
        float invd = ds[hd];
        float2 bv = *(const float2*)(bias + l16 * 2);
        float v0 = fmaf(acc0, invd, bv.x);
        float v1 = fmaf(acc1, invd, bv.y);
        if (EPI == 1) {
            float s0 = tanhf(ea[0]);
            if (s0 < 0.1f) s0 = 1.0f;
            s0 *= 1.05f;
            v0 *= s0; v1 *= s0;
            v0 = (v0 > 0.f) ? v0 : expm1f(v0);
            v1 = (v1 > 0.f) ? v1 : expm1f(v1);
            v0 = fminf(3.f, fmaxf(-3.f, v0));
            v1 = fminf(3.f, fmaxf(-3.f, v1));
        } else if (EPI == 2) {
            v0 = (v0 > 0.f) ? v0 : expm1f(v0);
            v1 = (v1 > 0.f) ? v1 : expm1f(v1);
            v0 = fminf(3.f, fmaxf(-3.f, v0));
            v1 = fminf(3.f, fmaxf(-3.f, v1));
        }
        *(float2*)(out + (size_t)node * 32 + l16 * 2) = make_float2(v0, v1);
    }
}

// ---------------------------------------------------------------------------
extern "C" void kernel_launch(void* const* d_in, const int* in_sizes, int n_in,
                              void* d_out, int out_size, void* d_ws, size_t ws_size,
                              hipStream_t stream) {
    const float* x   = (const float*)d_in[0];
    const int*   ei  = (const int*)d_in[1];
    const float* W1  = (const float*)d_in[2];
    const float* as1 = (const float*)d_in[3];
    const float* ad1 = (const float*)d_in[4];
    const float* b1  = (const float*)d_in[5];
    const float* ea1 = (const float*)d_in[6];
    const float* W2  = (const float*)d_in[7];
    const float* as2 = (const float*)d_in[8];
    const float* ad2 = (const float*)d_in[9];
    const float* b2  = (const float*)d_in[10];
    const float* W3  = (const float*)d_in[11];
    const float* as3 = (const float*)d_in[12];
    const float* ad3 = (const float*)d_in[13];
    const float* b3  = (const float*)d_in[14];
    float* out = (float*)d_out;

    const int n = in_sizes[0] / 32;   // 100000
    const int e = in_sizes[1] / 2;    // 3200000
    const int* src = ei;
    const int* dst = ei + e;
    const int nb = (n + NPB - 1) / NPB;   // 782 buckets

    char* w = (char*)d_ws;
    auto alloc = [&](size_t bytes) -> void* {
        void* p = (void*)w;
        w += (bytes + 255) & ~(size_t)255;
        return p;
    };
    __half* h16     = (__half*)alloc((size_t)n * 32 * 2);
    float* a_s      = (float*)alloc((size_t)n * 2 * 4);
    float* a_d      = (float*)alloc((size_t)n * 2 * 4);
    float* bufA     = (float*)alloc((size_t)n * 32 * 4);
    float* bufB     = (float*)alloc((size_t)n * 32 * 4);
    int2* rowinfo   = (int2*)alloc((size_t)n * 8);
    int* bucket_cur = (int*)alloc((size_t)(nb + 1) * 4);
    int* src_sorted = (int*)alloc((size_t)nb * CAPB * 4);
    unsigned int* pairs = (unsigned int*)bufA;   // aliased; consumed pre-layer1

    // ---- build CSR by dst (LDS-staged bucket binning, exact counts) ----
    hipMemsetAsync(bucket_cur, 0, (size_t)nb * 4, stream);   // relative cursors
    int e4 = e >> 2;
    k_bin<<<(e4 + 2047) / 2048, 1024, 0, stream>>>(src, dst, bucket_cur, pairs, e, nb);
    k_bucket_sort<<<nb, 512, 0, stream>>>(pairs, bucket_cur, rowinfo, src_sorted, n);

    const int tgrid = (n + 63) / 64;
    const int egrid = (n + 7) / 8;

    // ---- layer 1 ----
    k_transform<2><<<tgrid, 256, 0, stream>>>(x, W1, as1, ad1, h16, a_s, a_d, n);
    k_edge<2, 1><<<egrid, 256, 0, stream>>>(rowinfo, src_sorted, h16, a_s, a_d, b1, ea1, bufA, n, 0.01f);

    // ---- layer 2 ----
    k_transform<2><<<tgrid, 256, 0, stream>>>(bufA, W2, as2, ad2, h16, a_s, a_d, n);
    k_edge<2, 2><<<egrid, 256, 0, stream>>>(rowinfo, src_sorted, h16, a_s, a_d, b2, nullptr, bufB, n, 0.2f);

    // ---- layer 3 ----
    k_transform<1><<<tgrid, 256, 0, stream>>>(bufB, W3, as3, ad3, h16, a_s, a_d, n);
    k_edge<1, 0><<<egrid, 256, 0, stream>>>(rowinfo, src_sorted, h16, a_s, a_d, b3, nullptr, out, n, 0.2f);
}

// Round 6
// 335.645 us; speedup vs baseline: 1.2880x; 1.0967x over previous
//
#include <hip/hip_runtime.h>
#include <hip/hip_bf16.h>
#include <hip/hip_fp16.h>

// ---------------------------------------------------------------------------
// EnhancedRGCN (3-layer GAT), N=100000 nodes, E=3200000 edges, D=32.
// CSR-by-dst via FIXED-CAPACITY bucket binning (bucket = dst>>7, 128 nodes,
// CAPB=6144 slots). R13: k_bin LDS-staged bucket-grouped run writeback.
// R18: layer-1 transform OVERLAPPED with the CSR build — t1 is independent
// of the build, so its blocks ride along in the same launches:
//   fat1 = k_bin(391 blk) + t1 nodes [0,50016)  as 1563x 32-node blocks
//   fat2 = k_sort(782 blk) + t1 nodes [50016,n) as 3124x 16-node blocks
// (union'd LDS, disjoint blockIdx ranges; bin/sort are VMEM/atomic-latency
// bound, transform is LDS-issue bound -> co-resident overlap, and one fewer
// dispatch gap). transform_body is the PROVEN R13 code path (26us class;
// R16's VGPR-W and R17's 8-node-amortized variants both regressed and are
// reverted). k_edge byte-identical R13 (47.4us x3 control). No segment-max
// (shift-invariant softmax, bounded logits); no float atomics.
// ---------------------------------------------------------------------------

#define NPB  128    // nodes per bucket (dst>>7)
#define CAPB 6144   // slots per bucket (exact mean ~4092, >30 sigma room)
#define PAD_SENTINEL 0xFFFFFFFFu

// ---------------- shared transform body (R13-original code path) -----------
// NL nodes per block, NL*32 threads. Thread (nl,o) computes out channel o of
// node node0+nl. W staged to padded LDS, x staged coalesced (1 float/thread).
template <int H, int NL>
__device__ __forceinline__ void transform_body(
    const float* __restrict__ in, const float* __restrict__ W,
    const float* __restrict__ att_s, const float* __restrict__ att_d,
    __half* __restrict__ h16, float* __restrict__ a_s, float* __restrict__ a_d,
    int node0, int nlim, float (*Wl)[33], float (*xs)[32]) {
    constexpr int C = 32 / H;
    constexpr int NTH = NL * 32;
    int t = threadIdx.x;
    for (int i = t; i < 1024; i += NTH) Wl[i >> 5][i & 31] = W[i];
    int nl = t >> 5, o = t & 31;
    int node = node0 + nl;
    xs[nl][o] = (node < nlim) ? in[(size_t)node * 32 + o] : 0.f;
    __syncthreads();
    float acc = 0.f;
#pragma unroll
    for (int k = 0; k < 32; k++) acc = fmaf(xs[nl][k], Wl[o][k], acc);
    if (node < nlim) {
        h16[(size_t)node * 32 + o] = __float2half_rn(acc);
        float vs = acc * att_s[o];
        float vd = acc * att_d[o];
#pragma unroll
        for (int m = C / 2; m >= 1; m >>= 1) {
            vs += __shfl_xor(vs, m, 64);
            vd += __shfl_xor(vd, m, 64);
        }
        if ((o % C) == 0) {
            int hh = o / C;
            a_s[node * H + hh] = vs;
            a_d[node * H + hh] = vd;
        }
    }
}

// ---------------- fat1: k_bin (blocks < nbb)  ||  t1 first half ------------
__global__ void __launch_bounds__(1024)
k_bin_t1(const int* __restrict__ src, const int* __restrict__ dst,
         int* __restrict__ bucket_cursor, unsigned int* __restrict__ pairs,
         int e, int nb, int nbb,
         const float* __restrict__ in, const float* __restrict__ W,
         const float* __restrict__ att_s, const float* __restrict__ att_d,
         __half* __restrict__ h16, float* __restrict__ a_s,
         float* __restrict__ a_d, int nsplit) {
    __shared__ union {
        struct { int h[1024]; int bs[1024]; int cb[1024]; unsigned int stage[8192]; } b;
        struct { float Wl[32][33]; float xs[32][32]; } t;
    } sh;
    int t = threadIdx.x;
    if ((int)blockIdx.x >= nbb) {
        int node0 = ((int)blockIdx.x - nbb) * 32;
        transform_body<2, 32>(in, W, att_s, att_d, h16, a_s, a_d,
                              node0, nsplit, sh.t.Wl, sh.t.xs);
        return;
    }
    // ---- bin body (R13) ----
    sh.b.h[t] = 0;
    __syncthreads();
    int e4 = e >> 2;
    int base4 = blockIdx.x * 2048;          // 1024 threads x 2 int4 each
    int boff[8];                            // (bucket<<16) | rank, or -1
    unsigned int pk[8];
#pragma unroll
    for (int k = 0; k < 2; k++) {
        int i4 = base4 + k * 1024 + t;
        if (i4 < e4) {
            int4 dv = ((const int4*)dst)[i4];
            int4 sv = ((const int4*)src)[i4];
            const int* dd = (const int*)&dv;
            const int* ss = (const int*)&sv;
#pragma unroll
            for (int j = 0; j < 4; j++) {
                int q = 4 * k + j;
                int d = dd[j];
                int b = d >> 7;
                pk[q] = ((unsigned int)ss[j] << 7) | (unsigned int)(d & 127);
                int off = atomicAdd(&sh.b.h[b], 1);
                boff[q] = (b << 16) | off;
            }
        } else {
#pragma unroll
            for (int j = 0; j < 4; j++) boff[4 * k + j] = -1;
        }
    }
    __syncthreads();
    // global reservations overlap the scan (both only read h[])
    if (t >= 128 && t - 128 < nb) {
        int b = t - 128;
        int c = sh.b.h[b];
        sh.b.cb[b] = c ? atomicAdd(&bucket_cursor[b], c) : 0;
    }
    if (t < 64) {                           // wave 0: scan 1024 bins (16/lane)
        int sum = 0;
#pragma unroll
        for (int j = 0; j < 16; j++) sum += sh.b.h[t * 16 + j];
        int run = sum;
#pragma unroll
        for (int off = 1; off < 64; off <<= 1) {
            int v = __shfl_up(run, off, 64);
            if (t >= off) run += v;
        }
        int base = run - sum;               // exclusive
#pragma unroll
        for (int j = 0; j < 16; j++) {
            int b = t * 16 + j;
            sh.b.bs[b] = base;
            base += sh.b.h[b];
        }
    }
    __syncthreads();
#pragma unroll
    for (int q = 0; q < 8; q++) {           // scatter into bucket-grouped LDS
        if (boff[q] >= 0) {
            int b = boff[q] >> 16;
            sh.b.stage[sh.b.bs[b] + (boff[q] & 0xFFFF)] = pk[q];
        }
    }
    __syncthreads();
    // coalesced run writeback: wave w handles buckets w, w+16, ...
    int wv = t >> 6, ln = t & 63;
    for (int b = wv; b < nb; b += 16) {
        int c = sh.b.h[b];
        if (c == 0) continue;
        int gb = sh.b.cb[b];
        int room = CAPB - gb;               // overflow guard (relative cursor)
        if (c > room) c = (room > 0) ? room : 0;
        unsigned int* dp = pairs + (size_t)b * CAPB + gb;
        const unsigned int* sp = sh.b.stage + sh.b.bs[b];
        for (int o = ln; o < c; o += 64) dp[o] = sp[o];
    }
    if (blockIdx.x == 0 && t < (e & 3)) {   // tail (e not multiple of 4)
        int i = (e & ~3) + t;
        int d = dst[i];
        int b = d >> 7;
        int r = atomicAdd(&bucket_cursor[b], 1);
        if (r < CAPB)
            pairs[(size_t)b * CAPB + r] =
                ((unsigned int)src[i] << 7) | (unsigned int)(d & 127);
    }
}

// ---------------- fat2: k_bucket_sort (blocks < nb)  ||  t1 second half ----
__global__ void __launch_bounds__(512)
k_sort_t1(const unsigned int* __restrict__ pairs,
          const int* __restrict__ bucket_cursor,
          int2* __restrict__ rowinfo, int* __restrict__ src_sorted,
          int n, int nb,
          const float* __restrict__ in, const float* __restrict__ W,
          const float* __restrict__ att_s, const float* __restrict__ att_d,
          __half* __restrict__ h16, float* __restrict__ a_s,
          float* __restrict__ a_d, int nsplit) {
    __shared__ union {
        struct { int cnt[NPB]; int cur[NPB]; int total;
                 unsigned int lp[CAPB]; int op[CAPB]; } s;
        struct { float Wl[32][33]; float xs[16][32]; } t;
    } sh;
    int t = threadIdx.x;
    if ((int)blockIdx.x >= nb) {
        int node0 = nsplit + ((int)blockIdx.x - nb) * 16;
        transform_body<2, 16>(in, W, att_s, att_d, h16, a_s, a_d,
                              node0, n, sh.t.Wl, sh.t.xs);
        return;
    }
    // ---- sort body (R13) ----
    int b = blockIdx.x;
    int bbase = b * CAPB;
    int m = bucket_cursor[b];               // relative cursor = exact count
    if (m > CAPB) m = CAPB;
    if (t < NPB) sh.s.cnt[t] = 0;
    __syncthreads();
    for (int cb = 0; cb < m; cb += 4096) {
        unsigned int pv[8];
#pragma unroll
        for (int u = 0; u < 8; u++) {
            int i = cb + u * 512 + t;
            pv[u] = (i < m) ? pairs[bbase + i] : PAD_SENTINEL;
        }
#pragma unroll
        for (int u = 0; u < 8; u++) {
            int i = cb + u * 512 + t;
            if (i < m) sh.s.lp[i] = pv[u];
            if (pv[u] != PAD_SENTINEL) atomicAdd(&sh.s.cnt[pv[u] & 127], 1);
        }
    }
    __syncthreads();
    if (t < 64) {                       // wave 0 only: shfl scan over 128 bins
        int c0 = sh.s.cnt[2 * t];
        int c1 = sh.s.cnt[2 * t + 1];
        int sum = c0 + c1;
        int run = sum;
#pragma unroll
        for (int off = 1; off < 64; off <<= 1) {
            int v = __shfl_up(run, off, 64);
            if (t >= off) run += v;
        }
        int ex = run - sum;             // exclusive
        sh.s.cur[2 * t] = ex;
        sh.s.cur[2 * t + 1] = ex + c0;
        int node = b * NPB + 2 * t;
        if (node < n) rowinfo[node] = make_int2(bbase + ex, c0);
        if (node + 1 < n) rowinfo[node + 1] = make_int2(bbase + ex + c0, c1);
        if (t == 63) sh.s.total = run;  // dense entry count
    }
    __syncthreads();
    for (int cb = 0; cb < m; cb += 4096) {
        unsigned int pv[8];
        int of[8];
#pragma unroll
        for (int u = 0; u < 8; u++) {
            int i = cb + u * 512 + t;
            pv[u] = (i < m) ? sh.s.lp[i] : PAD_SENTINEL;
        }
#pragma unroll
        for (int u = 0; u < 8; u++)
            if (pv[u] != PAD_SENTINEL) of[u] = atomicAdd(&sh.s.cur[pv[u] & 127], 1);
#pragma unroll
        for (int u = 0; u < 8; u++)
            if (pv[u] != PAD_SENTINEL) sh.s.op[of[u]] = (int)(pv[u] >> 7);
    }
    __syncthreads();
    int nt4 = (sh.s.total + 3) >> 2;
    int4* dst4 = (int4*)(src_sorted + bbase);
    const int4* src4 = (const int4*)sh.s.op;
    for (int i = t; i < nt4; i += 512) dst4[i] = src4[i];
}

// ---------------- standalone per-layer dense transform (layers 2,3) --------
template <int H>
__global__ void k_transform(const float* __restrict__ in, const float* __restrict__ W,
                            const float* __restrict__ att_s, const float* __restrict__ att_d,
                            __half* __restrict__ h16, float* __restrict__ a_s,
                            float* __restrict__ a_d, int n) {
    __shared__ float Wl[32][33];
    __shared__ float xs[8][32];
    transform_body<H, 8>(in, W, att_s, att_d, h16, a_s, a_d,
                         blockIdx.x * 8, n, Wl, xs);
}

// ---------------- per-layer fused edge softmax + aggregation ----------------
// TWO NODES PER WAVE: half-wave (32 lanes) per node. 8 nodes per 256-block.
// Pass A: half-wave lane-per-edge (stride 32), stash (s,ex) per head in LDS
//         zero-padded to mult of 16; denominator partials.
// Pass B: 2 slots x 16 channel-lanes per node; 16 edges/node/iteration via
//         4 ds_read_b128 + 8 half2 gathers in flight + 16 fma_mix.
// Denominator: 5-level half-wave butterfly after pass B; acc: 1 level.
// EPI: 0 = bias only (layer3), 1 = layer1 epilogue, 2 = elu+clip (layer2).
template <int H, int EPI>
__global__ void k_edge(const int2* __restrict__ rowinfo, const int* __restrict__ src_sorted,
                       const __half* __restrict__ h16,
                       const float* __restrict__ a_s, const float* __restrict__ a_d,
                       const float* __restrict__ bias, const float* __restrict__ ea,
                       float* __restrict__ out, int n, float slope) {
    constexpr int CAP = 128;                  // entries per node per head
    constexpr int RSTR = 2 * CAP + 16;        // region stride in ints (+64B pad)
    __shared__ int lds_raw[8][H][RSTR];
    int nw = threadIdx.x >> 5;                // node slot 0..7
    int hl = threadIdx.x & 31;                // half-wave lane
    int node = blockIdx.x * 8 + nw;
    if (node >= n) return;
    int2 bi = rowinfo[node];
    int beg = bi.x, deg = bi.y;
    int padB = (deg + 15) & ~15;

    float ad[H];
#pragma unroll
    for (int hh = 0; hh < H; hh++) ad[hh] = a_d[node * H + hh];

    // ---- pass A: stash (s, ex) per head + denominator partials ----
    float ds[H];
#pragma unroll
    for (int hh = 0; hh < H; hh++) ds[hh] = 0.f;
    bool fast = (padB <= CAP);
    if (fast) {
        for (int idx = hl; idx < padB; idx += 32) {
            if (idx < deg) {
                int s = src_sorted[beg + idx];
                if (H == 2) {
                    float2 as2 = *(const float2*)((const char*)a_s + (unsigned)(s << 3));
                    float l0 = as2.x + ad[0]; l0 = fmaxf(l0, l0 * slope);
                    float l1 = as2.y + ad[1]; l1 = fmaxf(l1, l1 * slope);
                    float e0 = __expf(l0), e1 = __expf(l1);
                    ds[0] += e0; ds[1] += e1;
                    ((int2*)lds_raw[nw][0])[idx] = make_int2(s, __float_as_int(e0));
                    ((int2*)lds_raw[nw][H - 1])[idx] = make_int2(s, __float_as_int(e1));
                } else {
                    float l0 = a_s[s] + ad[0]; l0 = fmaxf(l0, l0 * slope);
                    float e0 = __expf(l0);
                    ds[0] += e0;
                    ((int2*)lds_raw[nw][0])[idx] = make_int2(s, __float_as_int(e0));
                }
            } else {
#pragma unroll
                for (int hh = 0; hh < H; hh++)
                    ((int2*)lds_raw[nw][hh])[idx] = make_int2(0, 0);
            }
        }
    } else {
        for (int idx = hl; idx < deg; idx += 32) {
            int s = src_sorted[beg + idx];
            if (H == 2) {
                float2 as2 = *(const float2*)((const char*)a_s + (unsigned)(s << 3));
                float l0 = as2.x + ad[0]; l0 = fmaxf(l0, l0 * slope);
                float l1 = as2.y + ad[1]; l1 = fmaxf(l1, l1 * slope);
                ds[0] += __expf(l0); ds[1] += __expf(l1);
            } else {
                float l0 = a_s[s] + ad[0]; l0 = fmaxf(l0, l0 * slope);
                ds[0] += __expf(l0);
            }
        }
    }

    // ---- pass B: 2 slots x 16 lanes per node; 16 edges/node/iteration ----
    int e2 = hl >> 4;          // slot 0/1
    int l16 = hl & 15;         // channel pair 0..15
    int hd = (H == 2) ? (l16 >> 3) : 0;
    int co = l16 << 2;
    float adh = ad[hd];
    float acc0 = 0.f, acc1 = 0.f;
    const char* hbase = (const char*)h16;
    const int* lb = &lds_raw[nw][hd][e2 * 4];   // entry offset 2*e2

    if (fast) {
        // slot e2 covers entries base + {0,1,4,5,8,9,12,13} + 2*e2
        for (int base = 0; base < padB; base += 16) {
            int4 qa = *(const int4*)(lb + base * 2);
            int4 qb = *(const int4*)(lb + base * 2 + 8);
            int4 qc = *(const int4*)(lb + base * 2 + 16);
            int4 qd = *(const int4*)(lb + base * 2 + 24);
            __half2 h0 = *(const __half2*)(hbase + (unsigned)((qa.x << 6) + co));
            __half2 h1 = *(const __half2*)(hbase + (unsigned)((qa.z << 6) + co));
            __half2 h2 = *(const __half2*)(hbase + (unsigned)((qb.x << 6) + co));
            __half2 h3 = *(const __half2*)(hbase + (unsigned)((qb.z << 6) + co));
            __half2 h4 = *(const __half2*)(hbase + (unsigned)((qc.x << 6) + co));
            __half2 h5 = *(const __half2*)(hbase + (unsigned)((qc.z << 6) + co));
            __half2 h6 = *(const __half2*)(hbase + (unsigned)((qd.x << 6) + co));
            __half2 h7 = *(const __half2*)(hbase + (unsigned)((qd.z << 6) + co));
            float xa0 = __int_as_float(qa.y), xa1 = __int_as_float(qa.w);
            float xb0 = __int_as_float(qb.y), xb1 = __int_as_float(qb.w);
            float xc0 = __int_as_float(qc.y), xc1 = __int_as_float(qc.w);
            float xd0 = __int_as_float(qd.y), xd1 = __int_as_float(qd.w);
            acc0 = fmaf(xa0, __half2float(__low2half(h0)), acc0);
            acc1 = fmaf(xa0, __half2float(__high2half(h0)), acc1);
            acc0 = fmaf(xa1, __half2float(__low2half(h1)), acc0);
            acc1 = fmaf(xa1, __half2float(__high2half(h1)), acc1);
            acc0 = fmaf(xb0, __half2float(__low2half(h2)), acc0);
            acc1 = fmaf(xb0, __half2float(__high2half(h2)), acc1);
            acc0 = fmaf(xb1, __half2float(__low2half(h3)), acc0);
            acc1 = fmaf(xb1, __half2float(__high2half(h3)), acc1);
            acc0 = fmaf(xc0, __half2float(__low2half(h4)), acc0);
            acc1 = fmaf(xc0, __half2float(__high2half(h4)), acc1);
            acc0 = fmaf(xc1, __half2float(__low2half(h5)), acc0);
            acc1 = fmaf(xc1, __half2float(__high2half(h5)), acc1);
            acc0 = fmaf(xd0, __half2float(__low2half(h6)), acc0);
            acc1 = fmaf(xd0, __half2float(__high2half(h6)), acc1);
            acc0 = fmaf(xd1, __half2float(__low2half(h7)), acc0);
            acc1 = fmaf(xd1, __half2float(__high2half(h7)), acc1);
        }
    } else {
        for (int base = 0; base < deg; base += 16) {
#pragma unroll
            for (int u = 0; u < 8; u++) {
                int idx = base + u * 2 + e2;
                int s = 0;
                float ex = 0.f;
                if (idx < deg) {
                    s = src_sorted[beg + idx];
                    float l = a_s[s * H + hd] + adh;
                    l = fmaxf(l, l * slope);
                    ex = __expf(l);
                }
                __half2 hv = *(const __half2*)(hbase + (unsigned)((s << 6) + co));
                acc0 = fmaf(ex, __half2float(__low2half(hv)), acc0);
                acc1 = fmaf(ex, __half2float(__high2half(hv)), acc1);
            }
        }
    }

    // ---- denominator reduction (5-level half-wave butterfly, deferred) ----
#pragma unroll
    for (int hh = 0; hh < H; hh++) {
        float v = ds[hh];
#pragma unroll
        for (int m = 16; m >= 1; m >>= 1) v += __shfl_xor(v, m, 64);
        ds[hh] = 1.f / (v + 1e-16f);
    }

    // ---- reduce accs across the 2 slots (1 level) ----
    acc0 += __shfl_xor(acc0, 16, 64);
    acc1 += __shfl_xor(acc1, 16, 64);

    if (l16 == hl) {           // hl < 16: slot-0 lanes hold the result
        float invd = ds[hd];
        float2 bv = *(const float2*)(bias + l16 * 2);
        float v0 = fmaf(acc0, invd, bv.x);
        float v1 = fmaf(acc1, invd, bv.y);
        if (EPI == 1) {
            float s0 = tanhf(ea[0]);
            if (s0 < 0.1f) s0 = 1.0f;
            s0 *= 1.05f;
            v0 *= s0; v1 *= s0;
            v0 = (v0 > 0.f) ? v0 : expm1f(v0);
            v1 = (v1 > 0.f) ? v1 : expm1f(v1);
            v0 = fminf(3.f, fmaxf(-3.f, v0));
            v1 = fminf(3.f, fmaxf(-3.f, v1));
        } else if (EPI == 2) {
            v0 = (v0 > 0.f) ? v0 : expm1f(v0);
            v1 = (v1 > 0.f) ? v1 : expm1f(v1);
            v0 = fminf(3.f, fmaxf(-3.f, v0));
            v1 = fminf(3.f, fmaxf(-3.f, v1));
        }
        *(float2*)(out + (size_t)node * 32 + l16 * 2) = make_float2(v0, v1);
    }
}

// ---------------------------------------------------------------------------
extern "C" void kernel_launch(void* const* d_in, const int* in_sizes, int n_in,
                              void* d_out, int out_size, void* d_ws, size_t ws_size,
                              hipStream_t stream) {
    const float* x   = (const float*)d_in[0];
    const int*   ei  = (const int*)d_in[1];
    const float* W1  = (const float*)d_in[2];
    const float* as1 = (const float*)d_in[3];
    const float* ad1 = (const float*)d_in[4];
    const float* b1  = (const float*)d_in[5];
    const float* ea1 = (const float*)d_in[6];
    const float* W2  = (const float*)d_in[7];
    const float* as2 = (const float*)d_in[8];
    const float* ad2 = (const float*)d_in[9];
    const float* b2  = (const float*)d_in[10];
    const float* W3  = (const float*)d_in[11];
    const float* as3 = (const float*)d_in[12];
    const float* ad3 = (const float*)d_in[13];
    const float* b3  = (const float*)d_in[14];
    float* out = (float*)d_out;

    const int n = in_sizes[0] / 32;   // 100000
    const int e = in_sizes[1] / 2;    // 3200000
    const int* src = ei;
    const int* dst = ei + e;
    const int nb = (n + NPB - 1) / NPB;   // 782 buckets

    char* w = (char*)d_ws;
    auto alloc = [&](size_t bytes) -> void* {
        void* p = (void*)w;
        w += (bytes + 255) & ~(size_t)255;
        return p;
    };
    __half* h16     = (__half*)alloc((size_t)n * 32 * 2);
    float* a_s      = (float*)alloc((size_t)n * 2 * 4);
    float* a_d      = (float*)alloc((size_t)n * 2 * 4);
    float* bufA     = (float*)alloc((size_t)n * 32 * 4);
    float* bufB     = (float*)alloc((size_t)n * 32 * 4);
    int2* rowinfo   = (int2*)alloc((size_t)n * 8);
    int* bucket_cur = (int*)alloc((size_t)(nb + 1) * 4);
    int* src_sorted = (int*)alloc((size_t)nb * CAPB * 4);
    unsigned int* pairs = (unsigned int*)bufA;   // aliased (spills into bufB;
                                                 // both consumed pre-layer1)

    // ---- t1 split: [0,nsplit) rides with k_bin; [nsplit,n) with k_sort ----
    int nsplit = n / 2;
    nsplit = (nsplit + 31) & ~31;
    if (nsplit > n) nsplit = n;
    const int t1a = (nsplit + 31) / 32;          // 32-node/1024-thr blocks
    const int t1b = (n - nsplit + 15) / 16;      // 16-node/512-thr blocks
    int e4 = e >> 2;
    const int nbb = (e4 + 2047) / 2048;          // 391 bin blocks

    hipMemsetAsync(bucket_cur, 0, (size_t)nb * 4, stream);   // relative cursors
    k_bin_t1<<<nbb + t1a, 1024, 0, stream>>>(src, dst, bucket_cur, pairs, e, nb, nbb,
                                             x, W1, as1, ad1, h16, a_s, a_d, nsplit);
    k_sort_t1<<<nb + t1b, 512, 0, stream>>>(pairs, bucket_cur, rowinfo, src_sorted, n, nb,
                                            x, W1, as1, ad1, h16, a_s, a_d, nsplit);

    const int tgrid = (n + 7) / 8;
    const int egrid = (n + 7) / 8;

    // ---- layer 1 edge ----
    k_edge<2, 1><<<egrid, 256, 0, stream>>>(rowinfo, src_sorted, h16, a_s, a_d, b1, ea1, bufA, n, 0.01f);

    // ---- layer 2 ----
    k_transform<2><<<tgrid, 256, 0, stream>>>(bufA, W2, as2, ad2, h16, a_s, a_d, n);
    k_edge<2, 2><<<egrid, 256, 0, stream>>>(rowinfo, src_sorted, h16, a_s, a_d, b2, nullptr, bufB, n, 0.2f);

    // ---- layer 3 ----
    k_transform<1><<<tgrid, 256, 0, stream>>>(bufB, W3, as3, ad3, h16, a_s, a_d, n);
    k_edge<1, 0><<<egrid, 256, 0, stream>>>(rowinfo, src_sorted, h16, a_s, a_d, b3, nullptr, out, n, 0.2f);
}